// Round 13
// baseline (101.019 us; speedup 1.0000x reference)
//
#include <hip/hip_runtime.h>

// Problem constants (from reference setup_inputs)
#define BB    2
#define CIN   64
#define NI    64
#define HIN   48
#define WIN   48
#define HO    96
#define WO    96
#define EPSN  1e-10f
#define IN_EPS 1e-5f
#define IMG   (HO*WO)     // 9216
#define NIMG  (BB*NI)     // 128

// Padded transposed input: xt[b][hp 0..49][wp 0..49][c 0..63], fp16.
// Input (h,w) -> (hp,wp) = (h+1,w+1); border cells are zeros.
#define XTROW 50
#define XTSL  (XTROW*XTROW*64)   // 160000 halves per batch

using half8  = __attribute__((ext_vector_type(8))) _Float16;
using half2v = __attribute__((ext_vector_type(2))) _Float16;
using f32x4  = __attribute__((ext_vector_type(4))) float;

__device__ _Float16 g_xt[BB * XTSL];        // 640 KB
__device__ _Float16 g_G[16 * 64 * 64];      // 128 KB folded fp16 weights [combo][i][c]
__device__ float    g_out[NIMG * IMG];      // 4.7 MB conv output (pre-bias)

// ---------------------------------------------------------------------------
// prep: blocks 0..95  : transpose x[b][c][h][:] -> xt[b][h+1][:][c] (fp16)
//       blocks 96..99 : zero rows hp=0 / hp=49
//       blocks 100..115: fold interior weights -> g_G[combo][i][c]
// ---------------------------------------------------------------------------
__global__ __launch_bounds__(256) void prep_kernel(const float* __restrict__ x,
                                                   const float* __restrict__ Wt) {
    const int blk = blockIdx.x;
    const int tid = threadIdx.x;

    if (blk < 96) {                      // transpose one input row (b, h)
        const int b = blk / 48, h = blk - 48 * b, hp = h + 1;
        __shared__ float sT[64][49];
        // load 64c x 48w into LDS (scalar LDS writes; reads are the hot side)
        for (int e = tid; e < 64 * 12; e += 256) {
            const int c = e / 12, w4 = e - 12 * c;
            const float4 t = *(const float4*)(x + ((size_t)(b * 64 + c) * 48 + h) * 48 + 4 * w4);
            sT[c][4 * w4]     = t.x;
            sT[c][4 * w4 + 1] = t.y;
            sT[c][4 * w4 + 2] = t.z;
            sT[c][4 * w4 + 3] = t.w;
        }
        __syncthreads();
        _Float16* xr = g_xt + (size_t)b * XTSL + (size_t)hp * (XTROW * 64);
        for (int e = tid; e < XTROW * 32; e += 256) {   // half2 units
            const int wp = e >> 5, cp = e & 31;
            half2v hv;
            if (wp == 0 || wp == 49) { hv[0] = (_Float16)0.f; hv[1] = (_Float16)0.f; }
            else { hv[0] = (_Float16)sT[2 * cp][wp - 1]; hv[1] = (_Float16)sT[2 * cp + 1][wp - 1]; }
            *(half2v*)(xr + wp * 64 + 2 * cp) = hv;
        }
        return;
    }
    if (blk < 100) {                     // zero guard rows
        const int z = blk - 96;
        const int b = z >> 1, hp = (z & 1) ? 49 : 0;
        _Float16* xr = g_xt + (size_t)b * XTSL + (size_t)hp * (XTROW * 64);
        half2v hz; hz[0] = (_Float16)0.f; hz[1] = (_Float16)0.f;
        for (int e = tid; e < XTROW * 32; e += 256)
            *(half2v*)(xr + (e >> 5) * 64 + 2 * (e & 31)) = hz;
        return;
    }
    // weight fold: combo = (py,px,a,bb); G[combo][i][c] = W[kh,kw]/(den+eps)
    const int combo = blk - 100;
    const int py = combo >> 3, px = (combo >> 2) & 1, a = (combo >> 1) & 1, bb = combo & 1;
    const int kh = 2 * a + 1 - py, kw = 2 * bb + 1 - px;
    for (int e = tid; e < 4096; e += 256) {
        const int i = e >> 6, c = e & 63;
        const float* wp = Wt + ((size_t)c * NI + i) * 16;
        float den = 0.f;
#pragma unroll
        for (int a2 = 0; a2 < 2; ++a2)
#pragma unroll
            for (int b2 = 0; b2 < 2; ++b2)
                den += wp[(2 * a2 + 1 - py) * 4 + (2 * b2 + 1 - px)];
        g_G[combo * 4096 + e] = (_Float16)(wp[kh * 4 + kw] / (den + EPSN));
    }
}

// ---------------------------------------------------------------------------
// gemm conv: 576 blocks x 64 threads (1 wave). Block = (b, input-row r,
// col-tile n0 of 16, i-half t0 of 32). Computes out[b][i0..i0+32][2r+py][..]
// for all 4 parities via 64 MFMA (16 combos x 2 N-tiles x 2 K-halves).
// A-fragment: lane m=l&15 = pixel u (col n0+u), k=(l>>4)*8+j = channel.
// B-fragment: lane n=l&15 = i-offset,          k likewise (g_G c-contiguous).
// D: col(=i)=l&15, row(=u)=(l>>4)*4+reg.
// ---------------------------------------------------------------------------
__global__ __launch_bounds__(64) void gemm_kernel() {
    const int blk = blockIdx.x;
    const int t0 = blk & 1;
    int rest = blk >> 1;
    const int n0 = (rest % 3) * 16; rest /= 3;
    const int r = rest % 48;
    const int b = rest / 48;
    const int i0 = 32 * t0;
    const int lane = threadIdx.x;
    const int il = lane & 15, q = lane >> 4;

    f32x4 acc[4][2];
#pragma unroll
    for (int p = 0; p < 4; ++p)
#pragma unroll
        for (int n = 0; n < 2; ++n) { acc[p][n][0] = 0.f; acc[p][n][1] = 0.f; acc[p][n][2] = 0.f; acc[p][n][3] = 0.f; }

    // base at shift (0,0): row hp=r+1, col wp=n0+il+1, channel q*8
    const _Float16* xbase = g_xt + (size_t)b * XTSL
                          + ((size_t)(r + 1) * XTROW + (n0 + il + 1)) * 64 + q * 8;
    const _Float16* gbase = g_G + (i0 + il) * 64 + q * 8;

#pragma unroll
    for (int khalf = 0; khalf < 2; ++khalf) {
        const int ko = khalf * 32;
        half8 A[3][3];
#pragma unroll
        for (int dr = 0; dr < 3; ++dr)
#pragma unroll
            for (int dc = 0; dc < 3; ++dc)
                A[dr][dc] = *(const half8*)(xbase + (dr - 1) * (XTROW * 64) + (dc - 1) * 64 + ko);

#pragma unroll
        for (int combo = 0; combo < 16; ++combo) {
            const int py = combo >> 3, px = (combo >> 2) & 1;
            const int a = (combo >> 1) & 1, bb = combo & 1;
            const int pi = combo >> 2;
            const half8 B0 = *(const half8*)(gbase + combo * 4096 + ko);
            const half8 B1 = *(const half8*)(gbase + combo * 4096 + 1024 + ko);
            const half8 Af = A[py - a + 1][px - bb + 1];
            acc[pi][0] = __builtin_amdgcn_mfma_f32_16x16x32_f16(Af, B0, acc[pi][0], 0, 0, 0);
            acc[pi][1] = __builtin_amdgcn_mfma_f32_16x16x32_f16(Af, B1, acc[pi][1], 0, 0, 0);
        }
    }

    // store: i = i0+16*nt+il; y = 2r+py; x = 2*n0 + 8*q + 2*reg + px
#pragma unroll
    for (int pi = 0; pi < 4; ++pi) {
        const int py = pi >> 1, px = pi & 1;
        const int y = 2 * r + py;
#pragma unroll
        for (int nt = 0; nt < 2; ++nt) {
            float* ob = g_out + (size_t)(b * 64 + i0 + 16 * nt + il) * IMG
                      + y * WO + 2 * n0 + 8 * q + px;
#pragma unroll
            for (int reg = 0; reg < 4; ++reg)
                ob[2 * reg] = acc[pi][nt][reg];
        }
    }
}

// ---------------------------------------------------------------------------
// epilogue: 128 blocks x 256. (1) fold boundary weights W*R -> LDS,
// (2) recompute 380 boundary pixels from xt, (3) stats over corrected image
// + bias, (4) normalize, write out.
// ---------------------------------------------------------------------------
__global__ __launch_bounds__(256) void epilogue_kernel(
        const float* __restrict__ Wt, const float* __restrict__ bias,
        float* __restrict__ out) {
    const int bi = blockIdx.x;
    const int b = bi >> 6, i = bi & 63;
    const int tid = threadIdx.x;

    __shared__ float sWb[16 * 4 * 64];   // [cls][tap][c]
    __shared__ float sFix[384];
    __shared__ float sRed[10];

    // ---- boundary weight fold ----
    for (int e = tid; e < 4096; e += 256) {
        const int cls = e >> 8, t = (e >> 6) & 3, c = e & 63;
        const int cy = cls >> 2, cx = cls & 3;
        const float* wp = Wt + ((size_t)c * NI + i) * 16;
        const int THn[4] = {1, 2, 2, 1};
        const int THv[4][2] = {{1, 1}, {0, 2}, {1, 3}, {2, 2}};
        float den = 0.f;
        for (int aa = 0; aa < THn[cy]; ++aa)
            for (int bb = 0; bb < THn[cx]; ++bb)
                den += wp[THv[cy][aa] * 4 + THv[cx][bb]];
        const int khA = (cy & 1) ? 0 : 1, kwA = (cx & 1) ? 0 : 1;
        const int kh = (t >> 1) ? khA + 2 : khA;
        const int kw = (t & 1) ? kwA + 2 : kwA;
        sWb[e] = wp[kh * 4 + kw] / (den + EPSN);
    }
    __syncthreads();

    // ---- boundary pixels: p = tid and tid+256 (tid<124) ----
    const _Float16* xb = g_xt + (size_t)b * XTSL;
#pragma unroll
    for (int k = 0; k < 2; ++k) {
        const int p = tid + 256 * k;
        if (p >= 380) break;
        int y, xo;
        if (p < 96)       { y = 0;            xo = p; }
        else if (p < 192) { y = 95;           xo = p - 96; }
        else if (p < 286) { y = p - 192 + 1;  xo = 0; }
        else              { y = p - 286 + 1;  xo = 95; }
        const int hpA = ((y + 1) >> 1) + 1, hpB = hpA - 1;
        const int wpA = ((xo + 1) >> 1) + 1, wpB = wpA - 1;
        const int cy = (y == 0) ? 0 : (y == 95) ? 3 : ((y & 1) ? 1 : 2);
        const int cx = (xo == 0) ? 0 : (xo == 95) ? 3 : ((xo & 1) ? 1 : 2);
        const float* w0 = &sWb[(cy * 4 + cx) * 256];
        const _Float16* pAA = xb + (hpA * XTROW + wpA) * 64;
        const _Float16* pAB = xb + (hpA * XTROW + wpB) * 64;
        const _Float16* pBA = xb + (hpB * XTROW + wpA) * 64;
        const _Float16* pBB = xb + (hpB * XTROW + wpB) * 64;
        float acc = 0.f;
#pragma unroll 8
        for (int c = 0; c < 64; ++c)
            acc += (float)pAA[c] * w0[c]       + (float)pAB[c] * w0[64 + c]
                 + (float)pBA[c] * w0[128 + c] + (float)pBB[c] * w0[192 + c];
        sFix[p] = acc;
    }
    __syncthreads();

    // ---- stats + normalize (36 px/thread) ----
    const float bv = bias[i];
    const float4* gb = (const float4*)(g_out + (size_t)bi * IMG);
    float4 v[9];
    float s1 = 0.f, s2 = 0.f;
#pragma unroll
    for (int k = 0; k < 9; ++k) {
        const int idx = k * 256 + tid;
        float4 t = gb[idx];
        const int p = 4 * idx;
        const int y = p / 96, xq = p - 96 * y;
        if (y == 0)       { t.x = sFix[xq]; t.y = sFix[xq + 1]; t.z = sFix[xq + 2]; t.w = sFix[xq + 3]; }
        else if (y == 95) { t.x = sFix[96 + xq]; t.y = sFix[97 + xq]; t.z = sFix[98 + xq]; t.w = sFix[99 + xq]; }
        else {
            if (xq == 0)  t.x = sFix[192 + y - 1];
            if (xq == 92) t.w = sFix[286 + y - 1];
        }
        t.x += bv; t.y += bv; t.z += bv; t.w += bv;
        v[k] = t;
        s1 += t.x + t.y + t.z + t.w;
        s2 += t.x * t.x + t.y * t.y + t.z * t.z + t.w * t.w;
    }

#pragma unroll
    for (int off = 32; off > 0; off >>= 1) {
        s1 += __shfl_down(s1, off, 64);
        s2 += __shfl_down(s2, off, 64);
    }
    const int w = tid >> 6;
    if ((tid & 63) == 0) { sRed[w] = s1; sRed[4 + w] = s2; }
    __syncthreads();
    if (tid == 0) {
        const float t1 = sRed[0] + sRed[1] + sRed[2] + sRed[3];
        const float t2 = sRed[4] + sRed[5] + sRed[6] + sRed[7];
        const float mean = t1 * (1.f / 9216.f);
        const float m2 = t2 * (1.f / 9216.f);
        sRed[8] = mean;
        sRed[9] = rsqrtf(m2 - mean * mean + IN_EPS);
    }
    __syncthreads();
    const float mean = sRed[8], inv = sRed[9];

    float4* ob = (float4*)out + (size_t)bi * (IMG / 4);
#pragma unroll
    for (int k = 0; k < 9; ++k) {
        float4 t = v[k];
        t.x = (t.x - mean) * inv; t.y = (t.y - mean) * inv;
        t.z = (t.z - mean) * inv; t.w = (t.w - mean) * inv;
        ob[k * 256 + tid] = t;
    }
}

extern "C" void kernel_launch(void* const* d_in, const int* in_sizes, int n_in,
                              void* d_out, int out_size, void* d_ws, size_t ws_size,
                              hipStream_t stream) {
    const float* x    = (const float*)d_in[0];
    const float* Wt   = (const float*)d_in[1];
    const float* bias = (const float*)d_in[2];
    float* out = (float*)d_out;
    (void)d_ws; (void)ws_size;

    prep_kernel<<<116, 256, 0, stream>>>(x, Wt);
    gemm_kernel<<<576, 64, 0, stream>>>();
    epilogue_kernel<<<128, 256, 0, stream>>>(Wt, bias, out);
}